// Round 5
// baseline (198.661 us; speedup 1.0000x reference)
//
#include <hip/hip_runtime.h>
#include <hip/hip_bf16.h>
#include <hip/hip_fp16.h>
#include <cstdint>

#define B_ 8
#define N_ 1024
#define D_ 256
#define H_ 8
#define HD_ 512   // H_*64

typedef _Float16 f16;
typedef _Float16 f16x8 __attribute__((ext_vector_type(8)));
typedef _Float16 f16x4 __attribute__((ext_vector_type(4)));
typedef float f32x4 __attribute__((ext_vector_type(4)));
typedef unsigned long long ull;
typedef unsigned long long ull2 __attribute__((ext_vector_type(2)));

// async global->LDS, 16B per lane.  dest = wave-uniform base + lane*16.
__device__ __forceinline__ void gload16(const void* g, void* l) {
    __builtin_amdgcn_global_load_lds(
        (const __attribute__((address_space(1))) unsigned int*)(uintptr_t)g,
        (__attribute__((address_space(3))) unsigned int*)(uintptr_t)l,
        16, 0, 0);
}

// DPP rotate within 16-lane row (VALU pipe, no LDS traffic)
template<int RN>
__device__ __forceinline__ float rowror(float x) {
    return __builtin_bit_cast(float, __builtin_amdgcn_mov_dpp(
        __builtin_bit_cast(int, x), 0x120 + RN, 0xf, 0xf, true));
}
__device__ __forceinline__ float rowmax16(float x) {
    x = fmaxf(x, rowror<1>(x)); x = fmaxf(x, rowror<2>(x));
    x = fmaxf(x, rowror<4>(x)); x = fmaxf(x, rowror<8>(x));
    return x;
}
__device__ __forceinline__ float rowsum16(float x) {
    x += rowror<1>(x); x += rowror<2>(x);
    x += rowror<4>(x); x += rowror<8>(x);
    return x;
}

// ---------------------------------------------------------------------------
// Pre-kernel A: bit-pack edge mask.  mask (B,N,N) f32 -> bmT[b][tt][row] u64
// ---------------------------------------------------------------------------
__global__ __launch_bounds__(256) void pack_mask_kernel(
    const float* __restrict__ mask, ull* __restrict__ bmT)
{
    const int wv = threadIdx.x >> 6, lane = threadIdx.x & 63;
    const int r = blockIdx.x * 4 + wv;
    const int b = r >> 10, n = r & 1023;
    const float* row = mask + ((size_t)b * N_ + n) * N_;
    for (int tt = 0; tt < 16; ++tt) {
        float v = row[tt * 64 + lane];
        ull m = __ballot(v != 0.0f);
        if (lane == 0) bmT[((size_t)b * 16 + tt) * N_ + n] = m;
    }
}

// ---------------------------------------------------------------------------
// Pre-kernel B: WTqkv[c][k] = f16(W[k][c&511] * (Q? 0.125 : 1)) via LDS
// transpose.  The 0.125 folds the attention scale into Q exactly (pow2).
// ---------------------------------------------------------------------------
__global__ __launch_bounds__(256) void wconv_qkv_kernel(
    const float* __restrict__ Wq, const float* __restrict__ Wk,
    const float* __restrict__ Wv, f16* __restrict__ WT)
{
    __shared__ float Ws[64][65];
    const int tid = threadIdx.x;
    const int c0 = blockIdx.x * 64, k0 = blockIdx.y * 64;
    const int m = c0 >> 9, cw0 = c0 & 511;
    const float* Wsel = (m == 0) ? Wq : (m == 1) ? Wk : Wv;
    const float scale = (m == 0) ? 0.125f : 1.0f;
    const int rr = tid >> 6, cc = tid & 63;
    for (int i = 0; i < 16; ++i)
        Ws[i * 4 + rr][cc] = Wsel[(size_t)(k0 + i * 4 + rr) * HD_ + cw0 + cc];
    __syncthreads();
    for (int i = 0; i < 16; ++i)
        WT[(size_t)(c0 + i * 4 + rr) * D_ + k0 + cc] = (f16)(Ws[cc][i * 4 + rr] * scale);
}

// Pre-kernel C: WToT[c][k] = f16(Wo[k][c]) via LDS transpose. Grid (4, 8).
__global__ __launch_bounds__(256) void wconv_o_kernel(
    const float* __restrict__ Wo, f16* __restrict__ WToT)
{
    __shared__ float Ws[64][65];
    const int tid = threadIdx.x;
    const int c0 = blockIdx.x * 64, k0 = blockIdx.y * 64;
    const int rr = tid >> 6, cc = tid & 63;
    for (int i = 0; i < 16; ++i)
        Ws[i * 4 + rr][cc] = Wo[(size_t)(k0 + i * 4 + rr) * D_ + c0 + cc];
    __syncthreads();
    for (int i = 0; i < 16; ++i)
        WToT[(size_t)(c0 + i * 4 + rr) * HD_ + k0 + cc] = (f16)Ws[cc][i * 4 + rr];
}

// Pre-kernel D: Xh = f16(X), 2M elements, 4 per thread.
__global__ __launch_bounds__(256) void xconv_kernel(
    const float* __restrict__ X, f16* __restrict__ Xh)
{
    const size_t i = (size_t)(blockIdx.x * 256 + threadIdx.x) * 4;
    f32x4 v = *reinterpret_cast<const f32x4*>(X + i);
    f16x4 h;
    for (int j = 0; j < 4; ++j) h[j] = (f16)v[j];
    *reinterpret_cast<f16x4*>(Xh + i) = h;
}

// ---------------------------------------------------------------------------
// Kernel 1: fused QKV.  Block 64 rows x 128 cols; wave owns a 32-col slice
// (64 rows) -> no cross-wave duplicate LDS reads.  W double-buffered via
// global_load_lds.  A-frags straight from Xh (f16, L2-hot).
// ---------------------------------------------------------------------------
__global__ __launch_bounds__(256, 4) void qkv_kernel(
    const f16* __restrict__ Xh, const f16* __restrict__ WT,
    f16* __restrict__ Qh, f16* __restrict__ Kh, f16* __restrict__ Vt)
{
    __shared__ f16 Wsh[2][8192];   // [bf][128 cols][64 k] swizzled 16B chunks
    const int tid = threadIdx.x;
    const int wv = tid >> 6, lane = tid & 63;
    const int g = lane >> 4, li = lane & 15;
    const int row0 = blockIdx.x * 64;
    const int c0 = blockIdx.y * 128;
    const int m = c0 >> 9, cw0 = c0 & 511;

    f32x4 acc[4][2] = {};

    auto stage = [&](int ks, int bf) {
        for (int i = 0; i < 4; ++i) {
            const int idx = i * 256 + tid;
            const int c = idx >> 3, ch = idx & 7;
            const f16* src = WT + (size_t)(c0 + c) * D_ + ks * 64 + ((ch ^ (c & 7)) * 8);
            gload16(src, &Wsh[bf][idx * 8]);
        }
    };
    stage(0, 0);
    __syncthreads();
    int bf = 0;
    for (int ks = 0; ks < 4; ++ks) {
        if (ks < 3) stage(ks + 1, bf ^ 1);
        for (int kk = 0; kk < 2; ++kk) {
            f16x8 af[4];
            for (int rf = 0; rf < 4; ++rf)
                af[rf] = *reinterpret_cast<const f16x8*>(
                    Xh + (size_t)(row0 + rf * 16 + li) * D_ + ks * 64 + kk * 32 + g * 8);
            for (int cf = 0; cf < 2; ++cf) {
                const int cl = wv * 32 + cf * 16 + li;
                f16x8 bm_ = *reinterpret_cast<const f16x8*>(
                    &Wsh[bf][cl * 64 + (((kk * 4 + g) ^ (cl & 7)) * 8)]);
                for (int rf = 0; rf < 4; ++rf)
                    acc[rf][cf] = __builtin_amdgcn_mfma_f32_16x16x32_f16(
                        af[rf], bm_, acc[rf][cf], 0, 0, 0);
            }
        }
        __syncthreads();
        bf ^= 1;
    }
    const int b = row0 >> 10;
    for (int cf = 0; cf < 2; ++cf) {
        const int cw = cw0 + wv * 32 + cf * 16 + li;
        const int h = cw >> 6, dk = cw & 63;
        for (int rf = 0; rf < 4; ++rf) {
            const int nloc = (row0 & 1023) + rf * 16 + g * 4;
            if (m < 2) {
                f16* dst = (m == 0 ? Qh : Kh) + ((size_t)(b * H_ + h) * N_ + nloc) * 64 + dk;
                for (int j = 0; j < 4; ++j) dst[(size_t)j * 64] = (f16)acc[rf][cf][j];
            } else {
                f16x4 v4;
                for (int j = 0; j < 4; ++j) v4[j] = (f16)acc[rf][cf][j];
                *reinterpret_cast<f16x4*>(
                    Vt + ((size_t)(b * H_ + h) * 64 + dk) * N_ + nloc) = v4;
            }
        }
    }
}

// ---------------------------------------------------------------------------
// Kernel 2: flash attention.  All stage pointers / LDS offsets hoisted;
// DPP rotate-reduce softmax in exp2 domain (scale folded into Q, log2e
// folded into dw).  K/V LDS double-buffered via global_load_lds.
// ---------------------------------------------------------------------------
__global__ __launch_bounds__(256, 4) void attn_kernel(
    const f16* __restrict__ Qh, const f16* __restrict__ Kh,
    const f16* __restrict__ Vt,
    const ull* __restrict__ bm, const float* __restrict__ dw,
    f16* __restrict__ AO)
{
    __shared__ f16 Ksh[8192];   // [2][64 rows][64] swizzled
    __shared__ f16 Vsh[8192];
    __shared__ f16 Ps[4096];    // [4 waves][16][64] swizzled
    const int tid = threadIdx.x;
    const int wv = tid >> 6, lane = tid & 63;
    const int g = lane >> 4, li = lane & 15;
    const int bid = (blockIdx.x & 7) * 128 + (blockIdx.x >> 3);  // XCD: 1 batch/XCD
    const int st = bid & 15, h = (bid >> 4) & 7, b = bid >> 7;
    const int s0 = st * 64 + wv * 16;

    const f16* Qbase = Qh + (size_t)(b * H_ + h) * N_ * 64;
    const f16* Kbase = Kh + (size_t)(b * H_ + h) * N_ * 64;
    const f16* Vbase = Vt + (size_t)(b * H_ + h) * 64 * N_;

    f16x8 qf0 = *reinterpret_cast<const f16x8*>(Qbase + (size_t)(s0 + li) * 64 + g * 8);
    f16x8 qf1 = *reinterpret_cast<const f16x8*>(Qbase + (size_t)(s0 + li) * 64 + 32 + g * 8);

    // ---- loop-invariant LDS offsets (elements) ----
    int ro0[4], ro1[4];
    for (int fc = 0; fc < 4; ++fc) {
        const int r = fc * 16 + li;
        ro0[fc] = r * 64 + ((g ^ (r & 7)) * 8);
        ro1[fc] = r * 64 + (((4 | g) ^ (r & 7)) * 8);
    }
    const int pr0 = wv * 1024 + li * 64 + ((g ^ (li & 7)) * 8);
    const int pr1 = wv * 1024 + li * 64 + (((4 | g) ^ (li & 7)) * 8);

    // ---- stage pointers (advance by fixed strides per tile) ----
    const int s0i = wv * 64 + lane, s1i = 256 + wv * 64 + lane;
    const int r0_ = s0i >> 3, c0_ = ((s0i & 7) ^ (r0_ & 7)) * 8;
    const int r1_ = s1i >> 3, c1_ = ((s1i & 7) ^ (r1_ & 7)) * 8;
    const f16* kp0 = Kbase + r0_ * 64 + c0_;
    const f16* kp1 = Kbase + r1_ * 64 + c1_;
    const f16* vp0 = Vbase + (size_t)r0_ * N_ + c0_;
    const f16* vp1 = Vbase + (size_t)r1_ * N_ + c1_;
    f16* const kd0 = Ksh + s0i * 8;
    f16* const kd1 = Ksh + s1i * 8;
    f16* const vd0 = Vsh + s0i * 8;
    f16* const vd1 = Vsh + s1i * 8;

    const ull* bmp = bm + (size_t)b * 16 * N_ + s0 + g * 4;
    const float* dwp = dw + b * N_ + li;

    f32x4 of[4] = {};
    float m_run[4], l_run[4];
    for (int j = 0; j < 4; ++j) { m_run[j] = -1e30f; l_run[j] = 0.f; }

    gload16(kp0, kd0); gload16(kp1, kd1);
    gload16(vp0, vd0); gload16(vp1, vd1);
    kp0 += 4096; kp1 += 4096; vp0 += 64; vp1 += 64;
    __syncthreads();
    int koff = 0;

    for (int tt = 0; tt < 16; ++tt) {
        if (tt < 15) {   // stage next tile into other buffer (drained by barrier)
            const int nb = koff ^ 4096;
            gload16(kp0, kd0 + nb); gload16(kp1, kd1 + nb);
            gload16(vp0, vd0 + nb); gload16(vp1, vd1 + nb);
            kp0 += 4096; kp1 += 4096; vp0 += 64; vp1 += 64;
        }
        ull2 w01 = *reinterpret_cast<const ull2*>(bmp);
        ull2 w23 = *reinterpret_cast<const ull2*>(bmp + 2);
        bmp += N_;
        float dwc[4], bdw[4];
        for (int fc = 0; fc < 4; ++fc) {
            dwc[fc] = dwp[fc * 16] * 1.442695041f;   // log2e folded in
            bdw[fc] = dwc[fc] * -1.0e9f;
        }
        dwp += 64;

        f32x4 s[4] = {};
        for (int fc = 0; fc < 4; ++fc) {
            f16x8 kf0 = *reinterpret_cast<const f16x8*>(Ksh + koff + ro0[fc]);
            f16x8 kf1 = *reinterpret_cast<const f16x8*>(Ksh + koff + ro1[fc]);
            s[fc] = __builtin_amdgcn_mfma_f32_16x16x32_f16(qf0, kf0, s[fc], 0, 0, 0);
            s[fc] = __builtin_amdgcn_mfma_f32_16x16x32_f16(qf1, kf1, s[fc], 0, 0, 0);
        }
        ull wsh[4];
        wsh[0] = w01.x >> li; wsh[1] = w01.y >> li;
        wsh[2] = w23.x >> li; wsh[3] = w23.y >> li;

        float mt[4] = {-1e30f, -1e30f, -1e30f, -1e30f};
        for (int fc = 0; fc < 4; ++fc)
            for (int j = 0; j < 4; ++j) {
                const float sel = ((wsh[j] >> (fc * 16)) & 1ull) ? 0.0f : bdw[fc];
                const float lg = fmaf(s[fc][j], dwc[fc], sel);   // log2-domain
                s[fc][j] = lg;
                mt[j] = fmaxf(mt[j], lg);
            }
        float alpha[4];
        for (int j = 0; j < 4; ++j) {
            mt[j] = rowmax16(mt[j]);
            const float mn = fmaxf(m_run[j], mt[j]);
            alpha[j] = __builtin_amdgcn_exp2f(m_run[j] - mn);
            m_run[j] = mn;
        }
        float rs[4] = {0.f, 0.f, 0.f, 0.f};
        for (int fc = 0; fc < 4; ++fc)
            for (int j = 0; j < 4; ++j) {
                const float p = __builtin_amdgcn_exp2f(s[fc][j] - m_run[j]);
                s[fc][j] = p;
                rs[j] += p;
            }
        for (int j = 0; j < 4; ++j) {
            rs[j] = rowsum16(rs[j]);
            l_run[j] = l_run[j] * alpha[j] + rs[j];
        }
        for (int fc = 0; fc < 4; ++fc)
            for (int j = 0; j < 4; ++j) of[fc][j] *= alpha[j];

        // P -> per-wave swizzled LDS -> A fragments (same-wave, no barrier)
        {
            f16* psw = Ps + wv * 1024;
            for (int fc = 0; fc < 4; ++fc)
                for (int j = 0; j < 4; ++j) {
                    const int r = g * 4 + j;
                    psw[r * 64 + (((fc * 2 + (li >> 3)) ^ (r & 7)) * 8) + (li & 7)]
                        = (f16)s[fc][j];
                }
            f16x8 pf0 = *reinterpret_cast<const f16x8*>(Ps + pr0);
            f16x8 pf1 = *reinterpret_cast<const f16x8*>(Ps + pr1);
            for (int fc = 0; fc < 4; ++fc) {
                f16x8 vf0 = *reinterpret_cast<const f16x8*>(Vsh + koff + ro0[fc]);
                f16x8 vf1 = *reinterpret_cast<const f16x8*>(Vsh + koff + ro1[fc]);
                of[fc] = __builtin_amdgcn_mfma_f32_16x16x32_f16(pf0, vf0, of[fc], 0, 0, 0);
                of[fc] = __builtin_amdgcn_mfma_f32_16x16x32_f16(pf1, vf1, of[fc], 0, 0, 0);
            }
        }
        __syncthreads();   // drains next-tile DMA + orders LDS buffer reuse
        koff ^= 4096;
    }
    for (int j = 0; j < 4; ++j) {
        const float inv = 1.f / l_run[j];
        const int srow = s0 + g * 4 + j;
        f16* dst = AO + ((size_t)b * N_ + srow) * HD_ + h * 64;
        for (int fc = 0; fc < 4; ++fc)
            dst[fc * 16 + li] = (f16)(of[fc][j] * inv);
    }
}

// ---------------------------------------------------------------------------
// Kernel 3: out = AO @ Wo + bo.  Block 16 rows x 256 cols, 4 waves (16x64).
// A staged once in LDS (swizzled); B from L2-resident WToT.
// ---------------------------------------------------------------------------
__global__ __launch_bounds__(256, 4) void proj_kernel(
    const f16* __restrict__ AO, const f16* __restrict__ WToT,
    const float* __restrict__ bo, float* __restrict__ out)
{
    __shared__ f16 Ash[16 * 512];
    const int tid = threadIdx.x;
    const int wv = tid >> 6, lane = tid & 63;
    const int g = lane >> 4, li = lane & 15;
    const int row0 = blockIdx.x * 16;
    const int c0 = wv * 64;

    for (int i = 0; i < 4; ++i) {
        const int idx = i * 256 + tid;
        const int r = idx >> 6, ch = idx & 63;
        const f16* src = AO + (size_t)(row0 + r) * HD_ + ((ch ^ (r & 7)) * 8);
        gload16(src, &Ash[idx * 8]);
    }
    __syncthreads();

    f32x4 acc[4] = {};
    for (int k0 = 0; k0 < HD_; k0 += 32) {
        const int cb = k0 >> 3;
        f16x8 af = *reinterpret_cast<const f16x8*>(
            &Ash[li * HD_ + (((cb + g) ^ (li & 7)) * 8)]);
        for (int fc = 0; fc < 4; ++fc) {
            f16x8 bf = *reinterpret_cast<const f16x8*>(
                WToT + (size_t)(c0 + fc * 16 + li) * HD_ + k0 + g * 8);
            acc[fc] = __builtin_amdgcn_mfma_f32_16x16x32_f16(af, bf, acc[fc], 0, 0, 0);
        }
    }
    for (int fc = 0; fc < 4; ++fc) {
        const int c = c0 + fc * 16 + li;
        const float bias = bo[c];
        for (int j = 0; j < 4; ++j)
            out[(size_t)(row0 + g * 4 + j) * D_ + c] = acc[fc][j] + bias;
    }
}

extern "C" void kernel_launch(void* const* d_in, const int* in_sizes, int n_in,
                              void* d_out, int out_size, void* d_ws, size_t ws_size,
                              hipStream_t stream) {
    const float* X    = (const float*)d_in[0];
    const float* mask = (const float*)d_in[1];
    const float* dwv  = (const float*)d_in[2];
    const float* Wq   = (const float*)d_in[3];
    const float* Wk   = (const float*)d_in[4];
    const float* Wv   = (const float*)d_in[5];
    const float* Wo   = (const float*)d_in[6];
    const float* bo   = (const float*)d_in[7];
    float* out = (float*)d_out;

    const size_t per = (size_t)B_ * H_ * N_ * 64;   // 4M halves each
    f16* Qh = (f16*)d_ws;
    f16* Kh = Qh + per;
    f16* Vt = Kh + per;
    f16* AO = Vt + per;
    f16* WToT = (f16*)d_ws;   // overlaps Qh; built AFTER attn (Qh dead)

    // d_out as early scratch (fully overwritten by proj at the end):
    //   [0,1MB) bmT | [1MB,1.75MB) WTqkv | [2MB,6MB) Xh
    ull* bmT   = (ull*)d_out;
    f16* WTqkv = (f16*)((char*)d_out + (1u << 20));
    f16* Xh    = (f16*)((char*)d_out + (2u << 20));

    pack_mask_kernel<<<dim3(2048), 256, 0, stream>>>(mask, bmT);
    wconv_qkv_kernel<<<dim3(24, 4), 256, 0, stream>>>(Wq, Wk, Wv, WTqkv);
    xconv_kernel<<<dim3(2048), 256, 0, stream>>>(X, Xh);
    qkv_kernel<<<dim3(128, 12), 256, 0, stream>>>(Xh, WTqkv, Qh, Kh, Vt);
    attn_kernel<<<dim3(1024), 256, 0, stream>>>(Qh, Kh, Vt, bmT, dwv, AO);
    wconv_o_kernel<<<dim3(4, 8), 256, 0, stream>>>(Wo, WToT);
    proj_kernel<<<dim3(512, 1), 256, 0, stream>>>(AO, WToT, bo, out);
}

// Round 6
// 172.667 us; speedup vs baseline: 1.1505x; 1.1505x over previous
//
#include <hip/hip_runtime.h>
#include <hip/hip_bf16.h>
#include <hip/hip_fp16.h>
#include <cstdint>

#define B_ 8
#define N_ 1024
#define D_ 256
#define H_ 8
#define HD_ 512   // H_*64

typedef _Float16 f16;
typedef _Float16 f16x8 __attribute__((ext_vector_type(8)));
typedef _Float16 f16x4 __attribute__((ext_vector_type(4)));
typedef float f32x4 __attribute__((ext_vector_type(4)));
typedef unsigned long long ull;
typedef unsigned long long ull2 __attribute__((ext_vector_type(2)));

// async global->LDS, 16B per lane.  dest = wave-uniform base + lane*16.
__device__ __forceinline__ void gload16(const void* g, void* l) {
    __builtin_amdgcn_global_load_lds(
        (const __attribute__((address_space(1))) unsigned int*)(uintptr_t)g,
        (__attribute__((address_space(3))) unsigned int*)(uintptr_t)l,
        16, 0, 0);
}

// DPP rotate within 16-lane row (VALU pipe, no LDS traffic)
template<int RN>
__device__ __forceinline__ float rowror(float x) {
    return __builtin_bit_cast(float, __builtin_amdgcn_mov_dpp(
        __builtin_bit_cast(int, x), 0x120 + RN, 0xf, 0xf, true));
}
__device__ __forceinline__ float rowmax16(float x) {
    x = fmaxf(x, rowror<1>(x)); x = fmaxf(x, rowror<2>(x));
    x = fmaxf(x, rowror<4>(x)); x = fmaxf(x, rowror<8>(x));
    return x;
}
__device__ __forceinline__ float rowsum16(float x) {
    x += rowror<1>(x); x += rowror<2>(x);
    x += rowror<4>(x); x += rowror<8>(x);
    return x;
}

// ---------------------------------------------------------------------------
// Fused pre-kernel: [0,2048) pack_mask | [2048,2144) wconv_qkv | rest xconv.
// ---------------------------------------------------------------------------
__global__ __launch_bounds__(256) void pre_kernel(
    const float* __restrict__ mask, ull* __restrict__ bmT,
    const float* __restrict__ Wq, const float* __restrict__ Wk,
    const float* __restrict__ Wv, f16* __restrict__ WT,
    const float* __restrict__ X, f16* __restrict__ Xh)
{
    __shared__ float Ws[64][65];
    const int bid = blockIdx.x;
    const int tid = threadIdx.x;
    if (bid < 2048) {
        // bit-pack edge mask: bmT[b][tt][row], bit t = mask[b][row][tt*64+t]!=0
        const int wv = tid >> 6, lane = tid & 63;
        const int r = bid * 4 + wv;
        const int b = r >> 10, n = r & 1023;
        const float* row = mask + ((size_t)b * N_ + n) * N_;
        for (int tt = 0; tt < 16; ++tt) {
            float v = row[tt * 64 + lane];
            ull m = __ballot(v != 0.0f);
            if (lane == 0) bmT[((size_t)b * 16 + tt) * N_ + n] = m;
        }
    } else if (bid < 2144) {
        // WTqkv[c][k] = f16(W[k][c&511] * (Q? 0.125 : 1)) via LDS transpose
        const int t = bid - 2048;
        const int c0 = (t % 24) * 64, k0 = (t / 24) * 64;
        const int m = c0 >> 9, cw0 = c0 & 511;
        const float* Wsel = (m == 0) ? Wq : (m == 1) ? Wk : Wv;
        const float scale = (m == 0) ? 0.125f : 1.0f;
        const int rr = tid >> 6, cc = tid & 63;
        for (int i = 0; i < 16; ++i)
            Ws[i * 4 + rr][cc] = Wsel[(size_t)(k0 + i * 4 + rr) * HD_ + cw0 + cc];
        __syncthreads();
        for (int i = 0; i < 16; ++i)
            WT[(size_t)(c0 + i * 4 + rr) * D_ + k0 + cc] =
                (f16)(Ws[cc][i * 4 + rr] * scale);
    } else {
        // Xh = f16(X)
        const size_t i = (size_t)((bid - 2144) * 256 + tid) * 4;
        f32x4 v = *reinterpret_cast<const f32x4*>(X + i);
        f16x4 h2;
        for (int j = 0; j < 4; ++j) h2[j] = (f16)v[j];
        *reinterpret_cast<f16x4*>(Xh + i) = h2;
    }
}

// Pre-kernel C: WToT[c][k] = f16(Wo[k][c]) via LDS transpose. Grid (4, 8).
__global__ __launch_bounds__(256) void wconv_o_kernel(
    const float* __restrict__ Wo, f16* __restrict__ WToT)
{
    __shared__ float Ws[64][65];
    const int tid = threadIdx.x;
    const int c0 = blockIdx.x * 64, k0 = blockIdx.y * 64;
    const int rr = tid >> 6, cc = tid & 63;
    for (int i = 0; i < 16; ++i)
        Ws[i * 4 + rr][cc] = Wo[(size_t)(k0 + i * 4 + rr) * D_ + c0 + cc];
    __syncthreads();
    for (int i = 0; i < 16; ++i)
        WToT[(size_t)(c0 + i * 4 + rr) * HD_ + k0 + cc] = (f16)Ws[cc][i * 4 + rr];
}

// ---------------------------------------------------------------------------
// Kernel 1: fused QKV.  Block 64 rows x 128 cols, 4 waves (wave: 64r x 32c).
// BOTH X-tile and W-tile double-buffered in LDS via global_load_lds (swizzled).
// ---------------------------------------------------------------------------
__global__ __launch_bounds__(256, 3) void qkv_kernel(
    const f16* __restrict__ Xh, const f16* __restrict__ WT,
    f16* __restrict__ Qh, f16* __restrict__ Kh, f16* __restrict__ Vt)
{
    __shared__ f16 Ash[2][4096];   // [bf][64 rows][64 k] swizzled
    __shared__ f16 Wsh[2][8192];   // [bf][128 cols][64 k] swizzled
    const int tid = threadIdx.x;
    const int wv = tid >> 6, lane = tid & 63;
    const int g = lane >> 4, li = lane & 15;
    const int row0 = blockIdx.x * 64;
    const int c0 = blockIdx.y * 128;
    const int m = c0 >> 9, cw0 = c0 & 511;

    f32x4 acc[4][2] = {};

    auto stage = [&](int ks, int bf) {
        for (int i = 0; i < 2; ++i) {           // A: 512 chunks, 2/thread
            const int idx = i * 256 + tid;
            const int r = idx >> 3, ch = idx & 7;
            const f16* src = Xh + (size_t)(row0 + r) * D_ + ks * 64 + ((ch ^ (r & 7)) * 8);
            gload16(src, &Ash[bf][idx * 8]);
        }
        for (int i = 0; i < 4; ++i) {           // B: 1024 chunks, 4/thread
            const int idx = i * 256 + tid;
            const int c = idx >> 3, ch = idx & 7;
            const f16* src = WT + (size_t)(c0 + c) * D_ + ks * 64 + ((ch ^ (c & 7)) * 8);
            gload16(src, &Wsh[bf][idx * 8]);
        }
    };
    stage(0, 0);
    __syncthreads();
    int bf = 0;
    for (int ks = 0; ks < 4; ++ks) {
        if (ks < 3) stage(ks + 1, bf ^ 1);
        for (int kk = 0; kk < 2; ++kk) {
            f16x8 af[4];
            for (int rf = 0; rf < 4; ++rf) {
                const int r = rf * 16 + li;
                af[rf] = *reinterpret_cast<const f16x8*>(
                    &Ash[bf][r * 64 + (((kk * 4 + g) ^ (r & 7)) * 8)]);
            }
            __builtin_amdgcn_s_setprio(1);
            for (int cf = 0; cf < 2; ++cf) {
                const int cl = wv * 32 + cf * 16 + li;
                f16x8 bm_ = *reinterpret_cast<const f16x8*>(
                    &Wsh[bf][cl * 64 + (((kk * 4 + g) ^ (cl & 7)) * 8)]);
                for (int rf = 0; rf < 4; ++rf)
                    acc[rf][cf] = __builtin_amdgcn_mfma_f32_16x16x32_f16(
                        af[rf], bm_, acc[rf][cf], 0, 0, 0);
            }
            __builtin_amdgcn_s_setprio(0);
        }
        __syncthreads();
        bf ^= 1;
    }
    const int b = row0 >> 10;
    for (int cf = 0; cf < 2; ++cf) {
        const int cw = cw0 + wv * 32 + cf * 16 + li;
        const int h = cw >> 6, dk = cw & 63;
        for (int rf = 0; rf < 4; ++rf) {
            const int nloc = (row0 & 1023) + rf * 16 + g * 4;
            if (m < 2) {
                f16* dst = (m == 0 ? Qh : Kh) + ((size_t)(b * H_ + h) * N_ + nloc) * 64 + dk;
                for (int j = 0; j < 4; ++j) dst[(size_t)j * 64] = (f16)acc[rf][cf][j];
            } else {
                f16x4 v4;
                for (int j = 0; j < 4; ++j) v4[j] = (f16)acc[rf][cf][j];
                *reinterpret_cast<f16x4*>(
                    Vt + ((size_t)(b * H_ + h) * 64 + dk) * N_ + nloc) = v4;
            }
        }
    }
}

// ---------------------------------------------------------------------------
// Kernel 2: flash attention.  Hoisted addresses, DPP reduce, exp2 domain,
// K/V LDS double-buffer, setprio around MFMA, defer-max skip-rescale (T13).
// ---------------------------------------------------------------------------
__global__ __launch_bounds__(256, 4) void attn_kernel(
    const f16* __restrict__ Qh, const f16* __restrict__ Kh,
    const f16* __restrict__ Vt,
    const ull* __restrict__ bm, const float* __restrict__ dw,
    f16* __restrict__ AO)
{
    __shared__ f16 Ksh[8192];   // [2][64 rows][64] swizzled
    __shared__ f16 Vsh[8192];
    __shared__ f16 Ps[4096];    // [4 waves][16][64] swizzled
    const int tid = threadIdx.x;
    const int wv = tid >> 6, lane = tid & 63;
    const int g = lane >> 4, li = lane & 15;
    const int bid = (blockIdx.x & 7) * 128 + (blockIdx.x >> 3);  // 1 batch/XCD
    const int st = bid & 15, h = (bid >> 4) & 7, b = bid >> 7;
    const int s0 = st * 64 + wv * 16;

    const f16* Qbase = Qh + (size_t)(b * H_ + h) * N_ * 64;
    const f16* Kbase = Kh + (size_t)(b * H_ + h) * N_ * 64;
    const f16* Vbase = Vt + (size_t)(b * H_ + h) * 64 * N_;

    f16x8 qf0 = *reinterpret_cast<const f16x8*>(Qbase + (size_t)(s0 + li) * 64 + g * 8);
    f16x8 qf1 = *reinterpret_cast<const f16x8*>(Qbase + (size_t)(s0 + li) * 64 + 32 + g * 8);

    int ro0[4], ro1[4];
    for (int fc = 0; fc < 4; ++fc) {
        const int r = fc * 16 + li;
        ro0[fc] = r * 64 + ((g ^ (r & 7)) * 8);
        ro1[fc] = r * 64 + (((4 | g) ^ (r & 7)) * 8);
    }
    const int pr0 = wv * 1024 + li * 64 + ((g ^ (li & 7)) * 8);
    const int pr1 = wv * 1024 + li * 64 + (((4 | g) ^ (li & 7)) * 8);

    const int s0i = wv * 64 + lane, s1i = 256 + wv * 64 + lane;
    const int r0_ = s0i >> 3, c0_ = ((s0i & 7) ^ (r0_ & 7)) * 8;
    const int r1_ = s1i >> 3, c1_ = ((s1i & 7) ^ (r1_ & 7)) * 8;
    const f16* kp0 = Kbase + r0_ * 64 + c0_;
    const f16* kp1 = Kbase + r1_ * 64 + c1_;
    const f16* vp0 = Vbase + (size_t)r0_ * N_ + c0_;
    const f16* vp1 = Vbase + (size_t)r1_ * N_ + c1_;
    f16* const kd0 = Ksh + s0i * 8;
    f16* const kd1 = Ksh + s1i * 8;
    f16* const vd0 = Vsh + s0i * 8;
    f16* const vd1 = Vsh + s1i * 8;

    const ull* bmp = bm + (size_t)b * 16 * N_ + s0 + g * 4;
    const float* dwp = dw + b * N_ + li;

    f32x4 of[4] = {};
    float m_run[4], l_run[4];
    for (int j = 0; j < 4; ++j) { m_run[j] = -1e30f; l_run[j] = 0.f; }

    gload16(kp0, kd0); gload16(kp1, kd1);
    gload16(vp0, vd0); gload16(vp1, vd1);
    kp0 += 4096; kp1 += 4096; vp0 += 64; vp1 += 64;
    __syncthreads();
    int koff = 0;

    for (int tt = 0; tt < 16; ++tt) {
        if (tt < 15) {
            const int nb = koff ^ 4096;
            gload16(kp0, kd0 + nb); gload16(kp1, kd1 + nb);
            gload16(vp0, vd0 + nb); gload16(vp1, vd1 + nb);
            kp0 += 4096; kp1 += 4096; vp0 += 64; vp1 += 64;
        }
        ull2 w01 = *reinterpret_cast<const ull2*>(bmp);
        ull2 w23 = *reinterpret_cast<const ull2*>(bmp + 2);
        bmp += N_;
        float dwc[4], bdw[4];
        for (int fc = 0; fc < 4; ++fc) {
            dwc[fc] = dwp[fc * 16] * 1.442695041f;   // log2e folded in
            bdw[fc] = dwc[fc] * -1.0e9f;
        }
        dwp += 64;

        f32x4 s[4] = {};
        __builtin_amdgcn_s_setprio(1);
        for (int fc = 0; fc < 4; ++fc) {
            f16x8 kf0 = *reinterpret_cast<const f16x8*>(Ksh + koff + ro0[fc]);
            f16x8 kf1 = *reinterpret_cast<const f16x8*>(Ksh + koff + ro1[fc]);
            s[fc] = __builtin_amdgcn_mfma_f32_16x16x32_f16(qf0, kf0, s[fc], 0, 0, 0);
            s[fc] = __builtin_amdgcn_mfma_f32_16x16x32_f16(qf1, kf1, s[fc], 0, 0, 0);
        }
        __builtin_amdgcn_s_setprio(0);

        ull wsh[4];
        wsh[0] = w01.x >> li; wsh[1] = w01.y >> li;
        wsh[2] = w23.x >> li; wsh[3] = w23.y >> li;

        float mt[4] = {-1e30f, -1e30f, -1e30f, -1e30f};
        for (int fc = 0; fc < 4; ++fc)
            for (int j = 0; j < 4; ++j) {
                const float sel = ((wsh[j] >> (fc * 16)) & 1ull) ? 0.0f : bdw[fc];
                const float lg = fmaf(s[fc][j], dwc[fc], sel);   // log2-domain
                s[fc][j] = lg;
                mt[j] = fmaxf(mt[j], lg);
            }
        for (int j = 0; j < 4; ++j) mt[j] = rowmax16(mt[j]);

        // T13 defer-max: only rescale when a row's max grew by > 8 (log2)
        const bool small = (mt[0] - m_run[0] <= 8.f) & (mt[1] - m_run[1] <= 8.f) &
                           (mt[2] - m_run[2] <= 8.f) & (mt[3] - m_run[3] <= 8.f);
        if (!__all(small)) {
            for (int j = 0; j < 4; ++j) {
                const float mn = fmaxf(m_run[j], mt[j]);
                const float alpha = __builtin_amdgcn_exp2f(m_run[j] - mn);
                m_run[j] = mn;
                l_run[j] *= alpha;
                for (int fc = 0; fc < 4; ++fc) of[fc][j] *= alpha;
            }
        }
        float rs[4] = {0.f, 0.f, 0.f, 0.f};
        for (int fc = 0; fc < 4; ++fc)
            for (int j = 0; j < 4; ++j) {
                const float p = __builtin_amdgcn_exp2f(s[fc][j] - m_run[j]);
                s[fc][j] = p;
                rs[j] += p;
            }
        for (int j = 0; j < 4; ++j)
            l_run[j] += rowsum16(rs[j]);

        // P -> per-wave swizzled LDS -> A fragments (same-wave, no barrier)
        {
            f16* psw = Ps + wv * 1024;
            for (int fc = 0; fc < 4; ++fc)
                for (int j = 0; j < 4; ++j) {
                    const int r = g * 4 + j;
                    psw[r * 64 + (((fc * 2 + (li >> 3)) ^ (r & 7)) * 8) + (li & 7)]
                        = (f16)s[fc][j];
                }
            f16x8 pf0 = *reinterpret_cast<const f16x8*>(Ps + pr0);
            f16x8 pf1 = *reinterpret_cast<const f16x8*>(Ps + pr1);
            __builtin_amdgcn_s_setprio(1);
            for (int fc = 0; fc < 4; ++fc) {
                f16x8 vf0 = *reinterpret_cast<const f16x8*>(Vsh + koff + ro0[fc]);
                f16x8 vf1 = *reinterpret_cast<const f16x8*>(Vsh + koff + ro1[fc]);
                of[fc] = __builtin_amdgcn_mfma_f32_16x16x32_f16(pf0, vf0, of[fc], 0, 0, 0);
                of[fc] = __builtin_amdgcn_mfma_f32_16x16x32_f16(pf1, vf1, of[fc], 0, 0, 0);
            }
            __builtin_amdgcn_s_setprio(0);
        }
        __syncthreads();   // drains next-tile DMA + orders LDS buffer reuse
        koff ^= 4096;
    }
    for (int j = 0; j < 4; ++j) {
        const float inv = 1.f / l_run[j];
        const int srow = s0 + g * 4 + j;
        f16* dst = AO + ((size_t)b * N_ + srow) * HD_ + h * 64;
        for (int fc = 0; fc < 4; ++fc)
            dst[fc * 16 + li] = (f16)(of[fc][j] * inv);
    }
}

// ---------------------------------------------------------------------------
// Kernel 3: out = AO @ Wo + bo.  Block 16 rows x 256 cols, 4 waves (16x64).
// A staged once in LDS (swizzled); B from L2-resident WToT.
// ---------------------------------------------------------------------------
__global__ __launch_bounds__(256, 4) void proj_kernel(
    const f16* __restrict__ AO, const f16* __restrict__ WToT,
    const float* __restrict__ bo, float* __restrict__ out)
{
    __shared__ f16 Ash[16 * 512];
    const int tid = threadIdx.x;
    const int wv = tid >> 6, lane = tid & 63;
    const int g = lane >> 4, li = lane & 15;
    const int row0 = blockIdx.x * 16;
    const int c0 = wv * 64;

    for (int i = 0; i < 4; ++i) {
        const int idx = i * 256 + tid;
        const int r = idx >> 6, ch = idx & 63;
        const f16* src = AO + (size_t)(row0 + r) * HD_ + ((ch ^ (r & 7)) * 8);
        gload16(src, &Ash[idx * 8]);
    }
    __syncthreads();

    f32x4 acc[4] = {};
    for (int k0 = 0; k0 < HD_; k0 += 32) {
        const int cb = k0 >> 3;
        f16x8 af = *reinterpret_cast<const f16x8*>(
            &Ash[li * HD_ + (((cb + g) ^ (li & 7)) * 8)]);
        for (int fc = 0; fc < 4; ++fc) {
            f16x8 bf = *reinterpret_cast<const f16x8*>(
                WToT + (size_t)(c0 + fc * 16 + li) * HD_ + k0 + g * 8);
            acc[fc] = __builtin_amdgcn_mfma_f32_16x16x32_f16(af, bf, acc[fc], 0, 0, 0);
        }
    }
    for (int fc = 0; fc < 4; ++fc) {
        const int c = c0 + fc * 16 + li;
        const float bias = bo[c];
        for (int j = 0; j < 4; ++j)
            out[(size_t)(row0 + g * 4 + j) * D_ + c] = acc[fc][j] + bias;
    }
}

extern "C" void kernel_launch(void* const* d_in, const int* in_sizes, int n_in,
                              void* d_out, int out_size, void* d_ws, size_t ws_size,
                              hipStream_t stream) {
    const float* X    = (const float*)d_in[0];
    const float* mask = (const float*)d_in[1];
    const float* dwv  = (const float*)d_in[2];
    const float* Wq   = (const float*)d_in[3];
    const float* Wk   = (const float*)d_in[4];
    const float* Wv   = (const float*)d_in[5];
    const float* Wo   = (const float*)d_in[6];
    const float* bo   = (const float*)d_in[7];
    float* out = (float*)d_out;

    const size_t per = (size_t)B_ * H_ * N_ * 64;   // 4M halves each
    f16* Qh = (f16*)d_ws;
    f16* Kh = Qh + per;
    f16* Vt = Kh + per;
    f16* AO = Vt + per;
    f16* WToT = (f16*)d_ws;   // overlaps Qh; built AFTER attn (Qh dead)

    // d_out as early scratch (fully overwritten by proj at the end):
    //   [0,1MB) bmT | [1MB,1.75MB) WTqkv | [2MB,6MB) Xh
    ull* bmT   = (ull*)d_out;
    f16* WTqkv = (f16*)((char*)d_out + (1u << 20));
    f16* Xh    = (f16*)((char*)d_out + (2u << 20));

    pre_kernel<<<dim3(2048 + 96 + 2048), 256, 0, stream>>>(
        mask, bmT, Wq, Wk, Wv, WTqkv, X, Xh);
    qkv_kernel<<<dim3(128, 12), 256, 0, stream>>>(Xh, WTqkv, Qh, Kh, Vt);
    attn_kernel<<<dim3(1024), 256, 0, stream>>>(Qh, Kh, Vt, bmT, dwv, AO);
    wconv_o_kernel<<<dim3(4, 8), 256, 0, stream>>>(Wo, WToT);
    proj_kernel<<<dim3(512, 1), 256, 0, stream>>>(AO, WToT, bo, out);
}